// Round 10
// baseline (201.559 us; speedup 1.0000x reference)
//
#include <hip/hip_runtime.h>

#define NPG 100     // nodes per graph
#define HF 64       // hidden width
#define ST 72       // Trm row stride (bf16): 64 + 8 pad (odd 16B units -> conflict-free b128)
#define SAT 136     // Tc row stride (bf16): 128 + 8 pad (odd 16B units -> conflict-free b128)
#define CMW 29      // count-matrix words per row (ODD -> conflict-free strided column reads)

typedef float  f4   __attribute__((ext_vector_type(4)));
typedef float  f16v __attribute__((ext_vector_type(16)));
typedef short  bf8  __attribute__((ext_vector_type(8)));

#define SZ_TC   (HF * SAT * 2)            // 17408 per Tc buffer
#define SZ_TRM  (128 * ST * 2)            // 18432 per Trm buffer
#define OFF_TC1  SZ_TC                    // Tc parity-1 @ 17408 (Cm overlays first 14848 B)
#define OFF_TRM0 (2 * SZ_TC)              // 34816
#define OFF_MISC (OFF_TRM0 + 2 * SZ_TRM)  // 71680
#define SMEM_BYTES (OFF_MISC + 1280)      // 72960 -> 2 blocks/CU by LDS
#define CMBYTES (128 * CMW * 4)           // 14848 <= SZ_TC
// misc: deg[112] u32 @0 (448) | pool[64] @448 | gvn[64] @704 | zf[32] @960
//       | logits[10] @1088 | lsep @1152

// bf16 weight workspace (d_ws), layout Wt[k5][fo][fi]:
//   W1t [5][64][16] @ 0 (fi zero-padded 3->16) | W2t [5][64][64] @ 5120 | W3t @ 25600
#define WT_TOTAL 46080

__device__ __forceinline__ unsigned short f2bf(float f) {
    unsigned u = __float_as_uint(f);
    u += 0x7fffu + ((u >> 16) & 1u);   // round-to-nearest-even
    return (unsigned short)(u >> 16);
}
// HW packed f32->bf16 (RNE), lo -> bits[15:0], hi -> bits[31:16].
__device__ __forceinline__ unsigned cvt_pk_bf16(float lo, float hi) {
    unsigned r;
    asm("v_cvt_pk_bf16_f32 %0, %1, %2" : "=v"(r) : "v"(lo), "v"(hi));
    return r;
}
__device__ __forceinline__ f16v zerov16() {
    f16v z;
    #pragma unroll
    for (int i = 0; i < 16; i++) z[i] = 0.f;
    return z;
}
// LDS-only barrier: lgkmcnt(0) drain + s_barrier. Keeps global (vmcnt) loads
// in flight across barriers; all intra-loop cross-wave traffic is LDS.
__device__ __forceinline__ void bar_lgkm() {
    asm volatile("s_waitcnt lgkmcnt(0)" ::: "memory");
    __builtin_amdgcn_s_barrier();
    __builtin_amdgcn_sched_barrier(0);
}
__device__ __forceinline__ void wait_lgkm() {
    asm volatile("s_waitcnt lgkmcnt(0)" ::: "memory");
}

union BF8U { unsigned u[4]; bf8 b; };

__global__ void wconv(const float* __restrict__ W1, const float* __restrict__ W2,
                      const float* __restrict__ W3, unsigned short* __restrict__ ws)
{
    int idx = blockIdx.x * 256 + threadIdx.x;
    if (idx >= WT_TOTAL) return;
    float v;
    if (idx < 5120) {
        int k5 = idx >> 10, rem = idx & 1023, fo = rem >> 4, fi = rem & 15;
        v = (fi < 3) ? W1[(k5 * 3 + fi) * HF + fo] : 0.f;
    } else if (idx < 25600) {
        int j = idx - 5120;
        int k5 = j >> 12, rem = j & 4095, fo = rem >> 6, fi = rem & 63;
        v = W2[(k5 * HF + fi) * HF + fo];
    } else {
        int j = idx - 25600;
        int k5 = j >> 12, rem = j & 4095, fo = rem >> 6, fi = rem & 63;
        v = W3[(k5 * HF + fi) * HF + fo];
    }
    ws[idx] = f2bf(v);
}

// EXACT R6 kernel (best verified: 18 windows, ping-pong parity, lgkm-only
// barriers, weight prefetch, wave-0 tail; dispatch 68us, absmax 0.015625)
// with ONE change: __launch_bounds__(256,2) -> (256,1).
// Rationale (R4/R6/R7/R8 calibration): (256,2)/(512,2) cap VGPR at 128;
// R6's ~140-reg live set under that cap spilled 6.25 MB of scratch writes
// onto the critical path. Occupancy is LDS-capped at 2 blocks/CU = 8 waves/CU
// regardless, and the VGPR pool (~2048/CU, steps at 64/128/256) sustains
// 8 waves/CU up to 256 regs -> relaxing the bound eliminates the spill at
// ZERO residency cost. (R9's LDS-readback alternative NaN'd; reverted.)
__launch_bounds__(256, 1)
__global__ void chebreg(const float* __restrict__ x, const int* __restrict__ ei,
                        const float* __restrict__ lambda_max,
                        const unsigned short* __restrict__ Wt,
                        const float* __restrict__ b1, const float* __restrict__ b2,
                        const float* __restrict__ b3,
                        const float* __restrict__ bng, const float* __restrict__ bnb,
                        const float* __restrict__ bnm, const float* __restrict__ bnv,
                        const float* __restrict__ fc1w, const float* __restrict__ fc1b,
                        const float* __restrict__ fc2w, const float* __restrict__ fc2b,
                        float* __restrict__ out, int E_total, int epg)
{
    extern __shared__ char sm[];
    const int tid = threadIdx.x;
    const int g = blockIdx.x;
    const int ebase = g * epg, nbase = g * NPG;
    const int wg = tid >> 6, lane = tid & 63;
    const int l31 = lane & 31, hh = lane >> 5;
    const int ht  = wg & 1;          // f-tile: cols 32*ht..+31
    const int Mt0 = (wg >> 1) * 2;   // n'-tile pair base
    const int fo  = ht * 32 + l31;

    unsigned* Cm   = (unsigned*)(sm + OFF_TC1);       // overlays Tc parity-1
    unsigned* deg  = (unsigned*)(sm + OFF_MISC);      // 112 u32
    float* pool    = (float*)(sm + OFF_MISC + 448);
    float* gvn     = (float*)(sm + OFF_MISC + 704);
    float* zf      = (float*)(sm + OFF_MISC + 960);
    float* logits  = (float*)(sm + OFF_MISC + 1088);
    float* lsep    = (float*)(sm + OFF_MISC + 1152);

    const float lam = lambda_max[g];
    const float two_l = 2.0f / lam;
    const float cl = two_l - 1.0f;

    // early x loads (consumed in W2; vmcnt rides across the W1 barrier)
    float xr0 = 0.f, xr1 = 0.f, xr2 = 0.f;
    const bool tv = (tid < NPG);
    if (tv) {
        xr0 = x[(nbase + tid) * 3 + 0];
        xr1 = x[(nbase + tid) * 3 + 1];
        xr2 = x[(nbase + tid) * 3 + 2];
    }

    // ---------------- W1: zero Tc0, Cm, Trm0, deg, pool ----------------
    // (Tc1 beyond Cm + Trm1 need no zero: fully overwritten at stage 1 before
    //  any read. Tc0 rows 3-63 MUST be zero; Trm0 garbage would inject NaN via
    //  0*NaN in MFMA -> zero it fully.)
    for (int i = tid; i < SZ_TC / 16; i += 256)
        ((f4*)sm)[i] = (f4){0.f, 0.f, 0.f, 0.f};
    for (int i = tid; i < CMBYTES / 16; i += 256)
        ((f4*)(sm + OFF_TC1))[i] = (f4){0.f, 0.f, 0.f, 0.f};
    for (int i = tid; i < SZ_TRM / 16; i += 256)
        ((f4*)(sm + OFF_TRM0))[i] = (f4){0.f, 0.f, 0.f, 0.f};
    if (tid < 112) deg[tid] = 0u;
    if (tid < HF) pool[tid] = 0.f;
    bar_lgkm();

    // ---------------- W2: edge atomics (Cm + deg) + T0-init ----------------
    for (int e = tid; e < epg; e += 256) {
        int r = ei[ebase + e] - nbase;
        int c = ei[E_total + ebase + e] - nbase;
        atomicAdd(&Cm[r * CMW + (c >> 2)], 1u << (8 * (c & 3)));
        atomicAdd(&deg[r], 1u);
    }
    if (tv) {
        unsigned short h0 = f2bf(xr0);
        unsigned short h1 = f2bf(xr1);
        unsigned short h2 = f2bf(xr2);
        *(unsigned*)(sm + OFF_TRM0 + (tid * ST) * 2) = (unsigned)h0 | ((unsigned)h1 << 16);
        *(unsigned short*)(sm + OFF_TRM0 + (tid * ST + 2) * 2) = h2;
        *(unsigned short*)(sm + (0 * SAT + tid) * 2) = h0;
        *(unsigned short*)(sm + (1 * SAT + tid) * 2) = h1;
        *(unsigned short*)(sm + (2 * SAT + tid) * 2) = h2;
    }
    bar_lgkm();

    // ---------------- W3: A-hat fragments (per-lane dis from deg) ----------------
    bf8 af[2][7];
    {
        int rr[2]; bool rv[2]; float base[2];
        #pragma unroll
        for (int m = 0; m < 2; m++) {
            rr[m] = 32 * (Mt0 + m) + l31;
            rv[m] = (rr[m] < NPG);
            unsigned dgr = rv[m] ? deg[rr[m]] : 0u;
            float disr = dgr ? rsqrtf((float)dgr) : 0.f;
            base[m] = rv[m] ? (-two_l * disr) : 0.f;
        }
        #pragma unroll
        for (int Ks = 0; Ks < 7; Ks++) {
            int k0 = Ks * 16 + 8 * hh;
            float dv8[8];
            #pragma unroll
            for (int j = 0; j < 8; j++) {
                unsigned dg = deg[k0 + j];
                dv8[j] = dg ? rsqrtf((float)dg) : 0.f;
            }
            #pragma unroll
            for (int m = 0; m < 2; m++) {
                unsigned w0 = rv[m] ? Cm[rr[m] * CMW + (k0 >> 2)]     : 0u;
                unsigned w1 = rv[m] ? Cm[rr[m] * CMW + (k0 >> 2) + 1] : 0u;
                float vv[8];
                #pragma unroll
                for (int j = 0; j < 8; j++) {
                    int k = k0 + j;
                    unsigned cnt = (((j < 4) ? w0 : w1) >> (8 * (k & 3))) & 255u;
                    float v = base[m] * (float)cnt * dv8[j];
                    if (rv[m] && k == rr[m]) v += cl;
                    vv[j] = v;
                }
                BF8U t;
                #pragma unroll
                for (int p = 0; p < 4; p++) t.u[p] = cvt_pk_bf16(vv[2 * p], vv[2 * p + 1]);
                af[m][Ks] = t.b;
            }
        }
    }
    // L0 k5=0 weight prefetch (consumed next window)
    bf8 bwp[4];
    bwp[0] = *(const bf8*)(Wt + fo * 16 + 8 * hh);
    bar_lgkm();   // Cm reads done before stage-1 writes clobber the Tc1 overlay

    // ---------------- 3 ChebConv layers ----------------
    f16v acc[2];
    unsigned prev[2][8], oldr[2][8];
    const float* bsv[3] = {b1, b2, b3};

    for (int L = 0; L < 3; L++) {
        const bool l1 = (L == 0);
        const unsigned short* Wl = l1 ? Wt : (Wt + (L == 1 ? 5120 : 25600));
        const int pb = L & 1;
        const int nKs = l1 ? 1 : 4;
        const float bias = bsv[L][fo];   // hoisted global load
        acc[0] = zerov16();
        acc[1] = zerov16();

        // prev = T0 at C-layout positions (L0 from Trm0; L>=1 already in regs)
        if (L == 0) {
            #pragma unroll
            for (int m = 0; m < 2; m++) {
                unsigned short tvv[16];
                #pragma unroll
                for (int r = 0; r < 16; r++) {
                    int np = (Mt0 + m) * 32 + (r & 3) + 8 * (r >> 2) + 4 * hh;
                    tvv[r] = *(const unsigned short*)(sm + OFF_TRM0 + (np * ST + fo) * 2);
                }
                #pragma unroll
                for (int p = 0; p < 8; p++)
                    prev[m][p] = (unsigned)tvv[2 * p] | ((unsigned)tvv[2 * p + 1] << 16);
            }
        }

        for (int s = 1; s <= 4; s++) {
            const int rp = (pb + s - 1) & 1, wp = rp ^ 1;
            const char* tcR = sm + rp * SZ_TC;
            const char* trR = sm + OFF_TRM0 + rp * SZ_TRM;
            char* tcW = sm + wp * SZ_TC;
            char* trW = sm + OFF_TRM0 + wp * SZ_TRM;

            // TW(s-1) with prefetched weights (bwp holds k5=s-1)
            #pragma unroll
            for (int Ks = 0; Ks < 4; Ks++) {
                if (Ks < nKs) {
                    #pragma unroll
                    for (int m = 0; m < 2; m++) {
                        bf8 a = *(const bf8*)(trR +
                                  (((Mt0 + m) * 32 + l31) * ST + Ks * 16 + 8 * hh) * 2);
                        acc[m] = __builtin_amdgcn_mfma_f32_32x32x16_bf16(a, bwp[Ks], acc[m], 0, 0, 0);
                    }
                }
            }
            // prefetch k5=s (in flight across this window's barrier)
            if (l1) {
                bwp[0] = *(const bf8*)(Wl + (s * 64 + fo) * 16 + 8 * hh);
            } else {
                #pragma unroll
                for (int Ks = 0; Ks < 4; Ks++)
                    bwp[Ks] = *(const bf8*)(Wl + (s * 64 + fo) * 64 + Ks * 16 + 8 * hh);
            }

            // B-frags: Tc[rp] rows (this lane's fo column set), b128
            bf8 bfr[7];
            #pragma unroll
            for (int Ks = 0; Ks < 7; Ks++)
                bfr[Ks] = *(const bf8*)(tcR + (fo * SAT + Ks * 16 + 8 * hh) * 2);

            #pragma unroll
            for (int m = 0; m < 2; m++) {
                f16v c = zerov16();
                #pragma unroll
                for (int Ks = 0; Ks < 7; Ks++)
                    c = __builtin_amdgcn_mfma_f32_32x32x16_bf16(af[m][Ks], bfr[Ks], c, 0, 0, 0);
                // Chebyshev recurrence + pack
                #pragma unroll
                for (int p = 0; p < 8; p++) {
                    float ve = c[2 * p], vo = c[2 * p + 1];
                    if (s >= 2) {
                        unsigned o = oldr[m][p];
                        ve = 2.f * ve - __uint_as_float(o << 16);
                        vo = 2.f * vo - __uint_as_float(o & 0xffff0000u);
                    }
                    oldr[m][p] = prev[m][p];
                    prev[m][p] = cvt_pk_bf16(ve, vo);
                }
                // Tc[wp] writes (node-quads -> 4x b64); dead at s==4
                if (s < 4) {
                    #pragma unroll
                    for (int q4 = 0; q4 < 4; q4++) {
                        int np0 = (Mt0 + m) * 32 + 8 * q4 + 4 * hh;
                        uint2 pk;
                        pk.x = prev[m][2 * q4];
                        pk.y = prev[m][2 * q4 + 1];
                        *(uint2*)(tcW + (fo * SAT + np0) * 2) = pk;
                    }
                }
                // Trm[wp] writes: b16 lo + b16 hi per packed pair
                #pragma unroll
                for (int p = 0; p < 8; p++) {
                    int r0 = 2 * p;
                    int npb = (Mt0 + m) * 32 + (r0 & 3) + 8 * (r0 >> 2) + 4 * hh;
                    char* ad = trW + (npb * ST + fo) * 2;
                    *(unsigned short*)ad = (unsigned short)prev[m][p];
                    *(unsigned short*)(ad + ST * 2) = (unsigned short)(prev[m][p] >> 16);
                }
            }
            bar_lgkm();   // single barrier: T_s visible + next-window WAR cover
        }

        // epi window: TW(4) reads Trm[pb] (T_4)
        {
            const char* trR = sm + OFF_TRM0 + pb * SZ_TRM;
            #pragma unroll
            for (int Ks = 0; Ks < 4; Ks++) {
                if (Ks < nKs) {
                    #pragma unroll
                    for (int m = 0; m < 2; m++) {
                        bf8 a = *(const bf8*)(trR +
                                  (((Mt0 + m) * 32 + l31) * ST + Ks * 16 + 8 * hh) * 2);
                        acc[m] = __builtin_amdgcn_mfma_f32_32x32x16_bf16(a, bwp[Ks], acc[m], 0, 0, 0);
                    }
                }
            }
        }

        if (L < 2) {
            // prefetch next layer's k5=0 (full 4-frag set)
            const unsigned short* Wn = Wt + (L == 0 ? 5120 : 25600);
            #pragma unroll
            for (int Ks = 0; Ks < 4; Ks++)
                bwp[Ks] = *(const bf8*)(Wn + fo * 64 + Ks * 16 + 8 * hh);

            const int op = pb ^ 1;
            char* tcW = sm + op * SZ_TC;
            char* trW = sm + OFF_TRM0 + op * SZ_TRM;
            #pragma unroll
            for (int m = 0; m < 2; m++) {
                #pragma unroll
                for (int p = 0; p < 8; p++) {
                    float ve = fmaxf(acc[m][2 * p]     + bias, 0.f);
                    float vo = fmaxf(acc[m][2 * p + 1] + bias, 0.f);
                    prev[m][p] = cvt_pk_bf16(ve, vo);
                }
                #pragma unroll
                for (int q4 = 0; q4 < 4; q4++) {
                    int np0 = (Mt0 + m) * 32 + 8 * q4 + 4 * hh;
                    uint2 pk;
                    pk.x = prev[m][2 * q4];
                    pk.y = prev[m][2 * q4 + 1];
                    *(uint2*)(tcW + (fo * SAT + np0) * 2) = pk;
                }
                #pragma unroll
                for (int p = 0; p < 8; p++) {
                    int r0 = 2 * p;
                    int npb = (Mt0 + m) * 32 + (r0 & 3) + 8 * (r0 >> 2) + 4 * hh;
                    char* ad = trW + (npb * ST + fo) * 2;
                    *(unsigned short*)ad = (unsigned short)prev[m][p];
                    *(unsigned short*)(ad + ST * 2) = (unsigned short)(prev[m][p] >> 16);
                }
            }
            bar_lgkm();   // T0' visible for next layer
        } else {
            float ssum = 0.f;
            #pragma unroll
            for (int m = 0; m < 2; m++) {
                #pragma unroll
                for (int r = 0; r < 16; r++) {
                    int np = (Mt0 + m) * 32 + (r & 3) + 8 * (r >> 2) + 4 * hh;
                    float h = fmaxf(acc[m][r] + bias, 0.f);
                    if (np < NPG) ssum += h;
                }
            }
            ssum += __shfl_xor(ssum, 32, 64);
            if (hh == 0) atomicAdd(&pool[fo], ssum);
            bar_lgkm();   // final barrier: pool visible to wave 0
        }
    }

    // ---------------- tail: wave 0 solo, wave-synchronous (no barriers) ----------------
    if (wg == 0) {
        float gv = pool[lane] * (1.0f / NPG);
        gv = (gv - bnm[lane]) * rsqrtf(bnv[lane] + 1e-5f) * bng[lane] + bnb[lane];
        gvn[lane] = gv;
        wait_lgkm();
        if (lane < 32) {
            float a = fc1b[lane];
            for (int f = 0; f < HF; f++) a += gvn[f] * fc1w[f * 32 + lane];
            zf[lane] = fmaxf(a, 0.f);
        }
        wait_lgkm();
        if (lane < 10) {
            float a = fc2b[lane];
            for (int k = 0; k < 32; k++) a += zf[k] * fc2w[k * 10 + lane];
            logits[lane] = a;
        }
        wait_lgkm();
        if (lane == 0) {
            float m = logits[0];
            for (int i = 1; i < 10; i++) m = fmaxf(m, logits[i]);
            float s = 0.f;
            for (int i = 0; i < 10; i++) s += expf(logits[i] - m);
            lsep[0] = m + logf(s);
        }
        wait_lgkm();
        if (lane < 10) out[g * 10 + lane] = logits[lane] - lsep[0];
    }
}

extern "C" void kernel_launch(void* const* d_in, const int* in_sizes, int n_in,
                              void* d_out, int out_size, void* d_ws, size_t ws_size,
                              hipStream_t stream) {
    const float* x    = (const float*)d_in[0];
    const int*   ei   = (const int*)d_in[1];
    const float* lmax = (const float*)d_in[3];
    const float* W1   = (const float*)d_in[4];
    const float* b1   = (const float*)d_in[5];
    const float* W2   = (const float*)d_in[6];
    const float* b2   = (const float*)d_in[7];
    const float* W3   = (const float*)d_in[8];
    const float* b3   = (const float*)d_in[9];
    const float* bng  = (const float*)d_in[10];
    const float* bnb  = (const float*)d_in[11];
    const float* bnm  = (const float*)d_in[12];
    const float* bnv  = (const float*)d_in[13];
    const float* fc1w = (const float*)d_in[14];
    const float* fc1b = (const float*)d_in[15];
    const float* fc2w = (const float*)d_in[16];
    const float* fc2b = (const float*)d_in[17];

    const int E = in_sizes[1] / 2;
    const int G = in_sizes[3];
    const int epg = E / G;

    unsigned short* Wt = (unsigned short*)d_ws;

    wconv<<<(WT_TOTAL + 255) / 256, 256, 0, stream>>>(W1, W2, W3, Wt);

    hipFuncSetAttribute((const void*)chebreg,
                        hipFuncAttributeMaxDynamicSharedMemorySize, SMEM_BYTES);

    chebreg<<<G, 256, SMEM_BYTES, stream>>>(x, ei, lmax, Wt, b1, b2, b3,
                                            bng, bnb, bnm, bnv, fc1w, fc1b, fc2w, fc2b,
                                            (float*)d_out, E, epg);
}

// Round 11
// 172.034 us; speedup vs baseline: 1.1716x; 1.1716x over previous
//
#include <hip/hip_runtime.h>

#define NPG 100     // nodes per graph
#define HF 64       // hidden width
#define SAT 136     // Tc row stride (bf16): 128 + 8 pad (17 units of 16B, odd -> conflict-free b128)
#define CMW 29      // count-matrix words per row (ODD -> conflict-free strided reads)

typedef float  f4   __attribute__((ext_vector_type(4)));
typedef float  f16v __attribute__((ext_vector_type(16)));
typedef short  bf8  __attribute__((ext_vector_type(8)));

#define SZ_TC   (HF * SAT * 2)            // 17408 per Tc buffer (T^T [f][node])
#define OFF_CM  (2 * SZ_TC)               // 34816 (Cm has its OWN region -- no overlay)
#define CMBYTES (128 * CMW * 4)           // 14848
#define OFF_MISC (OFF_CM + CMBYTES)       // 49664
#define SMEM_BYTES (OFF_MISC + 1280)      // 50944 -> 3 blocks/CU by LDS (152832 <= 160K)
// misc: deg[112] u32 @0 (448) | gvn[64] @448 | zf[32] @704 | logits[10] @832 | lsep @896

// bf16 weight workspace (d_ws), layout Wt[k5][fo][fi]:
//   W1t [5][64][16] @ 0 (fi zero-padded 3->16) | W2t [5][64][64] @ 5120 | W3t @ 25600
#define WT_TOTAL 46080

__device__ __forceinline__ unsigned short f2bf(float f) {
    unsigned u = __float_as_uint(f);
    u += 0x7fffu + ((u >> 16) & 1u);   // round-to-nearest-even
    return (unsigned short)(u >> 16);
}
// HW packed f32->bf16 (RNE), lo -> bits[15:0], hi -> bits[31:16].
__device__ __forceinline__ unsigned cvt_pk_bf16(float lo, float hi) {
    unsigned r;
    asm("v_cvt_pk_bf16_f32 %0, %1, %2" : "=v"(r) : "v"(lo), "v"(hi));
    return r;
}
__device__ __forceinline__ f16v zerov16() {
    f16v z;
    #pragma unroll
    for (int i = 0; i < 16; i++) z[i] = 0.f;
    return z;
}
// LDS-only barrier: lgkmcnt(0) drain + s_barrier (global loads ride vmcnt across).
__device__ __forceinline__ void bar_lgkm() {
    asm volatile("s_waitcnt lgkmcnt(0)" ::: "memory");
    __builtin_amdgcn_s_barrier();
    __builtin_amdgcn_sched_barrier(0);
}
__device__ __forceinline__ void wait_lgkm() {
    asm volatile("s_waitcnt lgkmcnt(0)" ::: "memory");
}

union BF8U { unsigned u[4]; bf8 b; };

__global__ void wconv(const float* __restrict__ W1, const float* __restrict__ W2,
                      const float* __restrict__ W3, unsigned short* __restrict__ ws)
{
    int idx = blockIdx.x * 256 + threadIdx.x;
    if (idx >= WT_TOTAL) return;
    float v;
    if (idx < 5120) {
        int k5 = idx >> 10, rem = idx & 1023, fo = rem >> 4, fi = rem & 15;
        v = (fi < 3) ? W1[(k5 * 3 + fi) * HF + fo] : 0.f;
    } else if (idx < 25600) {
        int j = idx - 5120;
        int k5 = j >> 12, rem = j & 4095, fo = rem >> 6, fi = rem & 63;
        v = W2[(k5 * HF + fi) * HF + fo];
    } else {
        int j = idx - 25600;
        int k5 = j >> 12, rem = j & 4095, fo = rem >> 6, fi = rem & 63;
        v = W3[(k5 * HF + fi) * HF + fo];
    }
    ws[idx] = f2bf(v);
}

// Transposed-dataflow ChebNet (R2's HW-VERIFIED numerics) on R6's window
// discipline, with the register live-set shrunk below the 128 cap:
//  - wave wg owns np = 32*wg + (lane&31); computes ALL 64 fo rows.
//  - LHAT: T_s^T[fo][np] via mfma(A = Tc[rp] row fo (b128, streamed 1-at-a-time),
//    B = afT Ahat^T frags in regs). C layout: col=np(own), row=fo.
//  - TW: B-frag built from prev[] REGISTERS via 2x v_permlane32_swap per Ks
//    (R2-verified construction, bit-exact absmax 0.015625); A = weights
//    (global, L2-hot, inline). ZERO LDS for TW -> Trm orientation DELETED.
//  - persistent regs: afT 28 + prev 16 + oldr 16 + acc 32 = 92; peak ~126
//    -> fits (256,2)'s 128 cap with NO spill (R6's 6.25MB scratch gone).
//  - Cm in its OWN LDS region (no overlay -> no lifetime hazard, and the
//    af-build needs no trailing barrier: it writes nothing). 17 windows.
//  - LDS 50944 B -> 3 blocks/CU by LDS; VGPR 128 allows 4 waves/SIMD.
__launch_bounds__(256, 2)
__global__ void chebreg(const float* __restrict__ x, const int* __restrict__ ei,
                        const float* __restrict__ lambda_max,
                        const unsigned short* __restrict__ Wt,
                        const float* __restrict__ b1, const float* __restrict__ b2,
                        const float* __restrict__ b3,
                        const float* __restrict__ bng, const float* __restrict__ bnb,
                        const float* __restrict__ bnm, const float* __restrict__ bnv,
                        const float* __restrict__ fc1w, const float* __restrict__ fc1b,
                        const float* __restrict__ fc2w, const float* __restrict__ fc2b,
                        float* __restrict__ out, int E_total, int epg)
{
    extern __shared__ char sm[];
    const int tid = threadIdx.x;
    const int g = blockIdx.x;
    const int ebase = g * epg, nbase = g * NPG;
    const int wg = tid >> 6, lane = tid & 63;
    const int l31 = lane & 31, hh = lane >> 5;
    const int np = 32 * wg + l31;
    const bool npv = (np < NPG);

    unsigned* Cm   = (unsigned*)(sm + OFF_CM);
    unsigned* deg  = (unsigned*)(sm + OFF_MISC);      // 112 u32
    float* gvn     = (float*)(sm + OFF_MISC + 448);
    float* zf      = (float*)(sm + OFF_MISC + 704);
    float* logits  = (float*)(sm + OFF_MISC + 832);
    float* lsep    = (float*)(sm + OFF_MISC + 896);

    const float lam = lambda_max[g];
    const float two_l = 2.0f / lam;
    const float cl = two_l - 1.0f;

    // early x loads (own-np indexed; consumed in W2, vmcnt rides the W1 barrier)
    float xr0 = 0.f, xr1 = 0.f, xr2 = 0.f;
    if (hh == 0 && npv) {
        xr0 = x[(nbase + np) * 3 + 0];
        xr1 = x[(nbase + np) * 3 + 1];
        xr2 = x[(nbase + np) * 3 + 2];
    }

    // ---------------- W1: zero Tc0 + Tc1 + Cm (contiguous) + deg ----------------
    for (int i = tid; i < (2 * SZ_TC + CMBYTES) / 16; i += 256)
        ((f4*)sm)[i] = (f4){0.f, 0.f, 0.f, 0.f};
    if (tid < 112) deg[tid] = 0u;
    bar_lgkm();

    // ---------------- W2: edge atomics (Cm + deg) + T0 = x^T into Tc0 ----------------
    for (int e = tid; e < epg; e += 256) {
        int r = ei[ebase + e] - nbase;
        int c = ei[E_total + ebase + e] - nbase;
        atomicAdd(&Cm[r * CMW + (c >> 2)], 1u << (8 * (c & 3)));
        atomicAdd(&deg[r], 1u);
    }
    unsigned prev[2][8], oldr[2][8];
    #pragma unroll
    for (int ct = 0; ct < 2; ct++)
        #pragma unroll
        for (int p = 0; p < 8; p++) { prev[ct][p] = 0u; oldr[ct][p] = 0u; }
    if (hh == 0 && npv) {
        prev[0][0] = cvt_pk_bf16(xr0, xr1);
        prev[0][1] = cvt_pk_bf16(xr2, 0.f);
        *(unsigned short*)(sm + (0 * SAT + np) * 2) = (unsigned short)(prev[0][0] & 0xffff);
        *(unsigned short*)(sm + (1 * SAT + np) * 2) = (unsigned short)(prev[0][0] >> 16);
        *(unsigned short*)(sm + (2 * SAT + np) * 2) = (unsigned short)(prev[0][1] & 0xffff);
    }
    bar_lgkm();

    // ---------------- af build (registers only -> NO trailing barrier) ----------------
    bf8 afT[7];
    {
        unsigned dgr = npv ? deg[np] : 0u;
        float disr = dgr ? rsqrtf((float)dgr) : 0.f;
        const float base = npv ? (-two_l * disr) : 0.f;
        #pragma unroll
        for (int Ks = 0; Ks < 7; Ks++) {
            int n0 = Ks * 16 + 8 * hh;
            unsigned w0 = npv ? Cm[np * CMW + (n0 >> 2)]     : 0u;
            unsigned w1 = npv ? Cm[np * CMW + (n0 >> 2) + 1] : 0u;
            float vv[8];
            #pragma unroll
            for (int j = 0; j < 8; j++) {
                int n = n0 + j;
                unsigned dg = deg[n];
                float dv = dg ? rsqrtf((float)dg) : 0.f;
                unsigned cnt = (((j < 4) ? w0 : w1) >> (8 * (n & 3))) & 255u;
                float v = base * (float)cnt * dv;
                if (npv && n == np) v += cl;
                vv[j] = v;
            }
            BF8U t;
            #pragma unroll
            for (int p = 0; p < 4; p++) t.u[p] = cvt_pk_bf16(vv[2 * p], vv[2 * p + 1]);
            afT[Ks] = t.b;
        }
    }

    // ---------------- 3 ChebConv layers ----------------
    f16v acc[2];
    const float* bsv[3] = {b1, b2, b3};

    for (int L = 0; L < 3; L++) {
        const bool l0 = (L == 0);
        const unsigned short* Wl = l0 ? Wt : (Wt + (L == 1 ? 5120 : 25600));
        const int wstr = l0 ? 16 : 64;
        const int nKs  = l0 ? 1 : 4;
        const int pb = L & 1;
        acc[0] = zerov16();
        acc[1] = zerov16();

        // TW B-frag from prev regs via permlane32_swap (R2-verified mapping).
        auto TWK = [&](int k5) {
            #pragma unroll
            for (int Ks = 0; Ks < 4; Ks++) {
                if (Ks < nKs) {
                    unsigned a0  = prev[Ks >> 1][4 * (Ks & 1) + 0];
                    unsigned b0  = prev[Ks >> 1][4 * (Ks & 1) + 2];
                    unsigned a1  = prev[Ks >> 1][4 * (Ks & 1) + 1];
                    unsigned b1v = prev[Ks >> 1][4 * (Ks & 1) + 3];
                    asm volatile("v_permlane32_swap_b32 %0, %1" : "+v"(a0), "+v"(b0));
                    asm volatile("v_permlane32_swap_b32 %0, %1" : "+v"(a1), "+v"(b1v));
                    BF8U bfr; bfr.u[0] = a0; bfr.u[1] = a1; bfr.u[2] = b0; bfr.u[3] = b1v;
                    #pragma unroll
                    for (int ct = 0; ct < 2; ct++) {
                        bf8 wf = *(const bf8*)(Wl + (k5 * 64 + 32 * ct + l31) * wstr
                                               + Ks * 16 + 8 * hh);
                        acc[ct] = __builtin_amdgcn_mfma_f32_32x32x16_bf16(wf, bfr.b, acc[ct], 0, 0, 0);
                    }
                }
            }
        };

        for (int s = 1; s <= 4; s++) {
            const int rp = (pb + s - 1) & 1, wp = rp ^ 1;
            const char* tcR = sm + rp * SZ_TC;
            char* tcW = sm + wp * SZ_TC;

            TWK(s - 1);   // consumes prev = T_{s-1} BEFORE recurrence update

            #pragma unroll
            for (int ct = 0; ct < 2; ct++) {
                if (l0 && ct == 1) continue;   // L0: T rows 32-63 stay zero
                // LHAT: A-frags streamed one-at-a-time (short live range)
                f16v c = zerov16();
                #pragma unroll
                for (int Ks = 0; Ks < 7; Ks++) {
                    bf8 A = *(const bf8*)(tcR + ((32 * ct + l31) * SAT + Ks * 16 + 8 * hh) * 2);
                    c = __builtin_amdgcn_mfma_f32_32x32x16_bf16(A, afT[Ks], c, 0, 0, 0);
                }
                const int pmax = l0 ? 2 : 8;
                #pragma unroll
                for (int p = 0; p < 8; p++) {
                    if (p < pmax) {
                        float ve = c[2 * p], vo = c[2 * p + 1];
                        if (s >= 2) {
                            unsigned o = oldr[ct][p];
                            ve = 2.f * ve - __uint_as_float(o << 16);
                            vo = 2.f * vo - __uint_as_float(o & 0xffff0000u);
                        }
                        oldr[ct][p] = prev[ct][p];
                        prev[ct][p] = cvt_pk_bf16(ve, vo);
                    }
                }
                // publish T_s -> Tc[wp] (dead at s==4: TWK(4) reads regs)
                if (s < 4) {
                    if (l0) {
                        if (hh == 0) {
                            *(unsigned short*)(tcW + (0 * SAT + np) * 2) = (unsigned short)(prev[0][0] & 0xffff);
                            *(unsigned short*)(tcW + (1 * SAT + np) * 2) = (unsigned short)(prev[0][0] >> 16);
                            *(unsigned short*)(tcW + (2 * SAT + np) * 2) = (unsigned short)(prev[0][1] & 0xffff);
                        }
                    } else {
                        #pragma unroll
                        for (int p = 0; p < 8; p++) {
                            int fo = 32 * ct + ((2 * p) & 3) + 8 * (p >> 1) + 4 * hh;
                            char* ad = tcW + (fo * SAT + np) * 2;
                            *(unsigned short*)ad = (unsigned short)(prev[ct][p] & 0xffff);
                            *(unsigned short*)(ad + SAT * 2) = (unsigned short)(prev[ct][p] >> 16);
                        }
                    }
                }
            }
            bar_lgkm();   // T_s visible; also WAR cover for next window
        }

        TWK(4);   // registers only -- no barrier needed

        if (L < 2) {
            // epilogue: ReLU+bias -> prev (= next T0) and Tc[pb^1]
            // (stage-4 barrier already fenced its reads of Tc[pb^1])
            const int op = pb ^ 1;
            char* tcW = sm + op * SZ_TC;
            const float* bl = bsv[L];
            #pragma unroll
            for (int ct = 0; ct < 2; ct++) {
                #pragma unroll
                for (int p = 0; p < 8; p++) {
                    int fo = 32 * ct + ((2 * p) & 3) + 8 * (p >> 1) + 4 * hh;
                    float2 bb = *(const float2*)(bl + fo);   // fo even -> 8B aligned
                    float ve = fmaxf(acc[ct][2 * p]     + bb.x, 0.f);
                    float vo = fmaxf(acc[ct][2 * p + 1] + bb.y, 0.f);
                    prev[ct][p] = cvt_pk_bf16(ve, vo);
                    char* ad = tcW + (fo * SAT + np) * 2;
                    *(unsigned short*)ad = (unsigned short)(prev[ct][p] & 0xffff);
                    *(unsigned short*)(ad + SAT * 2) = (unsigned short)(prev[ct][p] >> 16);
                }
            }
            bar_lgkm();   // T0' visible for next layer
        } else {
            // mean-pool scratch: f32 [64][132] overlays Tc0+Tc1 (33792 <= 34816);
            // stage-4 barrier drained all Tc reads.
            float* Sc = (float*)sm;
            const float* bl = bsv[2];
            #pragma unroll
            for (int ct = 0; ct < 2; ct++) {
                #pragma unroll
                for (int p = 0; p < 8; p++) {
                    int fo = 32 * ct + ((2 * p) & 3) + 8 * (p >> 1) + 4 * hh;
                    float2 bb = *(const float2*)(bl + fo);
                    float ve = fmaxf(acc[ct][2 * p]     + bb.x, 0.f);
                    float vo = fmaxf(acc[ct][2 * p + 1] + bb.y, 0.f);
                    if (npv) {
                        Sc[fo * 132 + np]       = ve;
                        Sc[(fo + 1) * 132 + np] = vo;
                    }
                }
            }
            bar_lgkm();   // Sc visible to wave 0
        }
    }

    // ---------------- tail: wave 0 solo, wave-synchronous ----------------
    if (wg == 0) {
        const float* Sc = (const float*)sm;
        float ssum = 0.f;
        #pragma unroll
        for (int k = 0; k < 25; k++) {
            f4 v = *(const f4*)(Sc + lane * 132 + 4 * k);
            ssum += v[0] + v[1] + v[2] + v[3];
        }
        float gv = ssum * (1.0f / NPG);
        gv = (gv - bnm[lane]) * rsqrtf(bnv[lane] + 1e-5f) * bng[lane] + bnb[lane];
        gvn[lane] = gv;
        wait_lgkm();
        if (lane < 32) {
            float a = fc1b[lane];
            for (int f = 0; f < HF; f++) a += gvn[f] * fc1w[f * 32 + lane];
            zf[lane] = fmaxf(a, 0.f);
        }
        wait_lgkm();
        if (lane < 10) {
            float a = fc2b[lane];
            for (int k = 0; k < 32; k++) a += zf[k] * fc2w[k * 10 + lane];
            logits[lane] = a;
        }
        wait_lgkm();
        if (lane == 0) {
            float m = logits[0];
            for (int i = 1; i < 10; i++) m = fmaxf(m, logits[i]);
            float s = 0.f;
            for (int i = 0; i < 10; i++) s += expf(logits[i] - m);
            lsep[0] = m + logf(s);
        }
        wait_lgkm();
        if (lane < 10) out[g * 10 + lane] = logits[lane] - lsep[0];
    }
}

extern "C" void kernel_launch(void* const* d_in, const int* in_sizes, int n_in,
                              void* d_out, int out_size, void* d_ws, size_t ws_size,
                              hipStream_t stream) {
    const float* x    = (const float*)d_in[0];
    const int*   ei   = (const int*)d_in[1];
    const float* lmax = (const float*)d_in[3];
    const float* W1   = (const float*)d_in[4];
    const float* b1   = (const float*)d_in[5];
    const float* W2   = (const float*)d_in[6];
    const float* b2   = (const float*)d_in[7];
    const float* W3   = (const float*)d_in[8];
    const float* b3   = (const float*)d_in[9];
    const float* bng  = (const float*)d_in[10];
    const float* bnb  = (const float*)d_in[11];
    const float* bnm  = (const float*)d_in[12];
    const float* bnv  = (const float*)d_in[13];
    const float* fc1w = (const float*)d_in[14];
    const float* fc1b = (const float*)d_in[15];
    const float* fc2w = (const float*)d_in[16];
    const float* fc2b = (const float*)d_in[17];

    const int E = in_sizes[1] / 2;
    const int G = in_sizes[3];
    const int epg = E / G;

    unsigned short* Wt = (unsigned short*)d_ws;

    wconv<<<(WT_TOTAL + 255) / 256, 256, 0, stream>>>(W1, W2, W3, Wt);

    hipFuncSetAttribute((const void*)chebreg,
                        hipFuncAttributeMaxDynamicSharedMemorySize, SMEM_BYTES);

    chebreg<<<G, 256, SMEM_BYTES, stream>>>(x, ei, lmax, Wt, b1, b2, b3,
                                            bng, bnb, bnm, bnv, fc1w, fc1b, fc2w, fc2b,
                                            (float*)d_out, E, epg);
}

// Round 12
// 154.451 us; speedup vs baseline: 1.3050x; 1.1138x over previous
//
#include <hip/hip_runtime.h>

#define NPG 100     // nodes per graph
#define HF 64       // hidden width
#define ST 72       // Trm row stride (bf16): 64 + 8 pad
#define SAT 136     // Tc row stride (bf16): 128 + 8 pad
#define CMW 29      // count-matrix words per row (ODD -> conflict-free strided reads)

typedef float  f4   __attribute__((ext_vector_type(4)));
typedef float  f16v __attribute__((ext_vector_type(16)));
typedef short  bf8  __attribute__((ext_vector_type(8)));

#define SZ_TC   (HF * SAT * 2)            // 17408 per Tc buffer
#define SZ_TRM  (128 * ST * 2)            // 18432 per Trm buffer
#define OFF_TC1  SZ_TC                    // Tc parity-1 @ 17408 (Cm overlays first 14848 B)
#define OFF_TRM0 (2 * SZ_TC)              // 34816
#define OFF_MISC (OFF_TRM0 + 2 * SZ_TRM)  // 71680
#define SMEM_BYTES (OFF_MISC + 1280)      // 72960 -> 2 blocks/CU
#define CMBYTES (128 * CMW * 4)           // 14848 <= SZ_TC
// misc: deg[112] u32 @0 (448) | pool[64] @448 | gvn[64] @704 | zf[32] @960
//       | logits[10] @1088 | lsep @1152

// bf16 weight workspace (d_ws), layout Wt[k5][fo][fi]:
//   W1t [5][64][16] @ 0 (fi zero-padded 3->16) | W2t [5][64][64] @ 5120 | W3t @ 25600
#define WT_TOTAL 46080

__device__ __forceinline__ unsigned short f2bf(float f) {
    unsigned u = __float_as_uint(f);
    u += 0x7fffu + ((u >> 16) & 1u);   // round-to-nearest-even
    return (unsigned short)(u >> 16);
}
// HW packed f32->bf16 (RNE), lo -> bits[15:0], hi -> bits[31:16].
__device__ __forceinline__ unsigned cvt_pk_bf16(float lo, float hi) {
    unsigned r;
    asm("v_cvt_pk_bf16_f32 %0, %1, %2" : "=v"(r) : "v"(lo), "v"(hi));
    return r;
}
__device__ __forceinline__ f16v zerov16() {
    f16v z;
    #pragma unroll
    for (int i = 0; i < 16; i++) z[i] = 0.f;
    return z;
}
// LDS-only barrier: lgkmcnt(0) drain + s_barrier. Keeps global (vmcnt) loads
// in flight across barriers; all intra-loop cross-wave traffic is LDS.
__device__ __forceinline__ void bar_lgkm() {
    asm volatile("s_waitcnt lgkmcnt(0)" ::: "memory");
    __builtin_amdgcn_s_barrier();
    __builtin_amdgcn_sched_barrier(0);
}
__device__ __forceinline__ void wait_lgkm() {
    asm volatile("s_waitcnt lgkmcnt(0)" ::: "memory");
}

union BF8U { unsigned u[4]; bf8 b; };

__global__ void wconv(const float* __restrict__ W1, const float* __restrict__ W2,
                      const float* __restrict__ W3, unsigned short* __restrict__ ws)
{
    int idx = blockIdx.x * 256 + threadIdx.x;
    if (idx >= WT_TOTAL) return;
    float v;
    if (idx < 5120) {
        int k5 = idx >> 10, rem = idx & 1023, fo = rem >> 4, fi = rem & 15;
        v = (fi < 3) ? W1[(k5 * 3 + fi) * HF + fo] : 0.f;
    } else if (idx < 25600) {
        int j = idx - 5120;
        int k5 = j >> 12, rem = j & 4095, fo = rem >> 6, fi = rem & 63;
        v = W2[(k5 * HF + fi) * HF + fo];
    } else {
        int j = idx - 25600;
        int k5 = j >> 12, rem = j & 4095, fo = rem >> 6, fi = rem & 63;
        v = W3[(k5 * HF + fi) * HF + fo];
    }
    ws[idx] = f2bf(v);
}

// EXACT R6 kernel (best across 11 rounds: 18 windows, ping-pong parity,
// lgkm-only barriers, weight prefetch, wave-0 tail; dispatch 68us, bench
// 157.5us) + ONE variable: s_setprio(1)/(0) around the MFMA clusters (T5).
// Mechanism: 2 INDEPENDENT blocks/CU run their windows out of phase; setprio
// lets a wave entering its MFMA chain win issue slots over the other block's
// staging waves (the attn case that measured +4-7%, not the lockstep null).
// Pure scheduler hint -> numerics bit-identical (absmax 0.015625).
__launch_bounds__(256, 2)
__global__ void chebreg(const float* __restrict__ x, const int* __restrict__ ei,
                        const float* __restrict__ lambda_max,
                        const unsigned short* __restrict__ Wt,
                        const float* __restrict__ b1, const float* __restrict__ b2,
                        const float* __restrict__ b3,
                        const float* __restrict__ bng, const float* __restrict__ bnb,
                        const float* __restrict__ bnm, const float* __restrict__ bnv,
                        const float* __restrict__ fc1w, const float* __restrict__ fc1b,
                        const float* __restrict__ fc2w, const float* __restrict__ fc2b,
                        float* __restrict__ out, int E_total, int epg)
{
    extern __shared__ char sm[];
    const int tid = threadIdx.x;
    const int g = blockIdx.x;
    const int ebase = g * epg, nbase = g * NPG;
    const int wg = tid >> 6, lane = tid & 63;
    const int l31 = lane & 31, hh = lane >> 5;
    const int ht  = wg & 1;          // f-tile: cols 32*ht..+31
    const int Mt0 = (wg >> 1) * 2;   // n'-tile pair base
    const int fo  = ht * 32 + l31;

    unsigned* Cm   = (unsigned*)(sm + OFF_TC1);       // overlays Tc parity-1
    unsigned* deg  = (unsigned*)(sm + OFF_MISC);      // 112 u32
    float* pool    = (float*)(sm + OFF_MISC + 448);
    float* gvn     = (float*)(sm + OFF_MISC + 704);
    float* zf      = (float*)(sm + OFF_MISC + 960);
    float* logits  = (float*)(sm + OFF_MISC + 1088);
    float* lsep    = (float*)(sm + OFF_MISC + 1152);

    const float lam = lambda_max[g];
    const float two_l = 2.0f / lam;
    const float cl = two_l - 1.0f;

    // early x loads (consumed in W2; vmcnt rides across the W1 barrier)
    float xr0 = 0.f, xr1 = 0.f, xr2 = 0.f;
    const bool tv = (tid < NPG);
    if (tv) {
        xr0 = x[(nbase + tid) * 3 + 0];
        xr1 = x[(nbase + tid) * 3 + 1];
        xr2 = x[(nbase + tid) * 3 + 2];
    }

    // ---------------- W1: zero Tc0, Cm, Trm0, deg, pool ----------------
    for (int i = tid; i < SZ_TC / 16; i += 256)
        ((f4*)sm)[i] = (f4){0.f, 0.f, 0.f, 0.f};
    for (int i = tid; i < CMBYTES / 16; i += 256)
        ((f4*)(sm + OFF_TC1))[i] = (f4){0.f, 0.f, 0.f, 0.f};
    for (int i = tid; i < SZ_TRM / 16; i += 256)
        ((f4*)(sm + OFF_TRM0))[i] = (f4){0.f, 0.f, 0.f, 0.f};
    if (tid < 112) deg[tid] = 0u;
    if (tid < HF) pool[tid] = 0.f;
    bar_lgkm();

    // ---------------- W2: edge atomics (Cm + deg) + T0-init ----------------
    for (int e = tid; e < epg; e += 256) {
        int r = ei[ebase + e] - nbase;
        int c = ei[E_total + ebase + e] - nbase;
        atomicAdd(&Cm[r * CMW + (c >> 2)], 1u << (8 * (c & 3)));
        atomicAdd(&deg[r], 1u);
    }
    if (tv) {
        unsigned short h0 = f2bf(xr0);
        unsigned short h1 = f2bf(xr1);
        unsigned short h2 = f2bf(xr2);
        *(unsigned*)(sm + OFF_TRM0 + (tid * ST) * 2) = (unsigned)h0 | ((unsigned)h1 << 16);
        *(unsigned short*)(sm + OFF_TRM0 + (tid * ST + 2) * 2) = h2;
        *(unsigned short*)(sm + (0 * SAT + tid) * 2) = h0;
        *(unsigned short*)(sm + (1 * SAT + tid) * 2) = h1;
        *(unsigned short*)(sm + (2 * SAT + tid) * 2) = h2;
    }
    bar_lgkm();

    // ---------------- W3: A-hat fragments (per-lane dis from deg) ----------------
    bf8 af[2][7];
    {
        int rr[2]; bool rv[2]; float base[2];
        #pragma unroll
        for (int m = 0; m < 2; m++) {
            rr[m] = 32 * (Mt0 + m) + l31;
            rv[m] = (rr[m] < NPG);
            unsigned dgr = rv[m] ? deg[rr[m]] : 0u;
            float disr = dgr ? rsqrtf((float)dgr) : 0.f;
            base[m] = rv[m] ? (-two_l * disr) : 0.f;
        }
        #pragma unroll
        for (int Ks = 0; Ks < 7; Ks++) {
            int k0 = Ks * 16 + 8 * hh;
            float dv8[8];
            #pragma unroll
            for (int j = 0; j < 8; j++) {
                unsigned dg = deg[k0 + j];
                dv8[j] = dg ? rsqrtf((float)dg) : 0.f;
            }
            #pragma unroll
            for (int m = 0; m < 2; m++) {
                unsigned w0 = rv[m] ? Cm[rr[m] * CMW + (k0 >> 2)]     : 0u;
                unsigned w1 = rv[m] ? Cm[rr[m] * CMW + (k0 >> 2) + 1] : 0u;
                float vv[8];
                #pragma unroll
                for (int j = 0; j < 8; j++) {
                    int k = k0 + j;
                    unsigned cnt = (((j < 4) ? w0 : w1) >> (8 * (k & 3))) & 255u;
                    float v = base[m] * (float)cnt * dv8[j];
                    if (rv[m] && k == rr[m]) v += cl;
                    vv[j] = v;
                }
                BF8U t;
                #pragma unroll
                for (int p = 0; p < 4; p++) t.u[p] = cvt_pk_bf16(vv[2 * p], vv[2 * p + 1]);
                af[m][Ks] = t.b;
            }
        }
    }
    // L0 k5=0 weight prefetch (consumed next window)
    bf8 bwp[4];
    bwp[0] = *(const bf8*)(Wt + fo * 16 + 8 * hh);
    bar_lgkm();   // Cm reads done before stage-1 writes clobber the Tc1 overlay

    // ---------------- 3 ChebConv layers ----------------
    f16v acc[2];
    unsigned prev[2][8], oldr[2][8];
    const float* bsv[3] = {b1, b2, b3};

    for (int L = 0; L < 3; L++) {
        const bool l1 = (L == 0);
        const unsigned short* Wl = l1 ? Wt : (Wt + (L == 1 ? 5120 : 25600));
        const int pb = L & 1;
        const int nKs = l1 ? 1 : 4;
        const float bias = bsv[L][fo];   // hoisted global load
        acc[0] = zerov16();
        acc[1] = zerov16();

        // prev = T0 at C-layout positions (L0 from Trm0; L>=1 already in regs)
        if (L == 0) {
            #pragma unroll
            for (int m = 0; m < 2; m++) {
                unsigned short tvv[16];
                #pragma unroll
                for (int r = 0; r < 16; r++) {
                    int np = (Mt0 + m) * 32 + (r & 3) + 8 * (r >> 2) + 4 * hh;
                    tvv[r] = *(const unsigned short*)(sm + OFF_TRM0 + (np * ST + fo) * 2);
                }
                #pragma unroll
                for (int p = 0; p < 8; p++)
                    prev[m][p] = (unsigned)tvv[2 * p] | ((unsigned)tvv[2 * p + 1] << 16);
            }
        }

        for (int s = 1; s <= 4; s++) {
            const int rp = (pb + s - 1) & 1, wp = rp ^ 1;
            const char* tcR = sm + rp * SZ_TC;
            const char* trR = sm + OFF_TRM0 + rp * SZ_TRM;
            char* tcW = sm + wp * SZ_TC;
            char* trW = sm + OFF_TRM0 + wp * SZ_TRM;

            // TW(s-1) with prefetched weights (bwp holds k5=s-1)
            __builtin_amdgcn_s_setprio(1);
            #pragma unroll
            for (int Ks = 0; Ks < 4; Ks++) {
                if (Ks < nKs) {
                    #pragma unroll
                    for (int m = 0; m < 2; m++) {
                        bf8 a = *(const bf8*)(trR +
                                  (((Mt0 + m) * 32 + l31) * ST + Ks * 16 + 8 * hh) * 2);
                        acc[m] = __builtin_amdgcn_mfma_f32_32x32x16_bf16(a, bwp[Ks], acc[m], 0, 0, 0);
                    }
                }
            }
            __builtin_amdgcn_s_setprio(0);
            // prefetch k5=s (in flight across this window's barrier)
            if (l1) {
                bwp[0] = *(const bf8*)(Wl + (s * 64 + fo) * 16 + 8 * hh);
            } else {
                #pragma unroll
                for (int Ks = 0; Ks < 4; Ks++)
                    bwp[Ks] = *(const bf8*)(Wl + (s * 64 + fo) * 64 + Ks * 16 + 8 * hh);
            }

            // B-frags: Tc[rp] rows (this lane's fo column set), b128
            bf8 bfr[7];
            #pragma unroll
            for (int Ks = 0; Ks < 7; Ks++)
                bfr[Ks] = *(const bf8*)(tcR + (fo * SAT + Ks * 16 + 8 * hh) * 2);

            #pragma unroll
            for (int m = 0; m < 2; m++) {
                f16v c = zerov16();
                __builtin_amdgcn_s_setprio(1);
                #pragma unroll
                for (int Ks = 0; Ks < 7; Ks++)
                    c = __builtin_amdgcn_mfma_f32_32x32x16_bf16(af[m][Ks], bfr[Ks], c, 0, 0, 0);
                __builtin_amdgcn_s_setprio(0);
                // Chebyshev recurrence + pack
                #pragma unroll
                for (int p = 0; p < 8; p++) {
                    float ve = c[2 * p], vo = c[2 * p + 1];
                    if (s >= 2) {
                        unsigned o = oldr[m][p];
                        ve = 2.f * ve - __uint_as_float(o << 16);
                        vo = 2.f * vo - __uint_as_float(o & 0xffff0000u);
                    }
                    oldr[m][p] = prev[m][p];
                    prev[m][p] = cvt_pk_bf16(ve, vo);
                }
                // Tc[wp] writes (node-quads -> 4x b64); dead at s==4
                if (s < 4) {
                    #pragma unroll
                    for (int q4 = 0; q4 < 4; q4++) {
                        int np0 = (Mt0 + m) * 32 + 8 * q4 + 4 * hh;
                        uint2 pk;
                        pk.x = prev[m][2 * q4];
                        pk.y = prev[m][2 * q4 + 1];
                        *(uint2*)(tcW + (fo * SAT + np0) * 2) = pk;
                    }
                }
                // Trm[wp] writes: b16 lo + b16 hi per packed pair
                #pragma unroll
                for (int p = 0; p < 8; p++) {
                    int r0 = 2 * p;
                    int npb = (Mt0 + m) * 32 + (r0 & 3) + 8 * (r0 >> 2) + 4 * hh;
                    char* ad = trW + (npb * ST + fo) * 2;
                    *(unsigned short*)ad = (unsigned short)prev[m][p];
                    *(unsigned short*)(ad + ST * 2) = (unsigned short)(prev[m][p] >> 16);
                }
            }
            bar_lgkm();   // single barrier: T_s visible + next-window WAR cover
        }

        // epi window: TW(4) reads Trm[pb] (T_4)
        {
            const char* trR = sm + OFF_TRM0 + pb * SZ_TRM;
            __builtin_amdgcn_s_setprio(1);
            #pragma unroll
            for (int Ks = 0; Ks < 4; Ks++) {
                if (Ks < nKs) {
                    #pragma unroll
                    for (int m = 0; m < 2; m++) {
                        bf8 a = *(const bf8*)(trR +
                                  (((Mt0 + m) * 32 + l31) * ST + Ks * 16 + 8 * hh) * 2);
                        acc[m] = __builtin_amdgcn_mfma_f32_32x32x16_bf16(a, bwp[Ks], acc[m], 0, 0, 0);
                    }
                }
            }
            __builtin_amdgcn_s_setprio(0);
        }

        if (L < 2) {
            // prefetch next layer's k5=0 (full 4-frag set)
            const unsigned short* Wn = Wt + (L == 0 ? 5120 : 25600);
            #pragma unroll
            for (int Ks = 0; Ks < 4; Ks++)
                bwp[Ks] = *(const bf8*)(Wn + fo * 64 + Ks * 16 + 8 * hh);

            const int op = pb ^ 1;
            char* tcW = sm + op * SZ_TC;
            char* trW = sm + OFF_TRM0 + op * SZ_TRM;
            #pragma unroll
            for (int m = 0; m < 2; m++) {
                #pragma unroll
                for (int p = 0; p < 8; p++) {
                    float ve = fmaxf(acc[m][2 * p]     + bias, 0.f);
                    float vo = fmaxf(acc[m][2 * p + 1] + bias, 0.f);
                    prev[m][p] = cvt_pk_bf16(ve, vo);
                }
                #pragma unroll
                for (int q4 = 0; q4 < 4; q4++) {
                    int np0 = (Mt0 + m) * 32 + 8 * q4 + 4 * hh;
                    uint2 pk;
                    pk.x = prev[m][2 * q4];
                    pk.y = prev[m][2 * q4 + 1];
                    *(uint2*)(tcW + (fo * SAT + np0) * 2) = pk;
                }
                #pragma unroll
                for (int p = 0; p < 8; p++) {
                    int r0 = 2 * p;
                    int npb = (Mt0 + m) * 32 + (r0 & 3) + 8 * (r0 >> 2) + 4 * hh;
                    char* ad = trW + (npb * ST + fo) * 2;
                    *(unsigned short*)ad = (unsigned short)prev[m][p];
                    *(unsigned short*)(ad + ST * 2) = (unsigned short)(prev[m][p] >> 16);
                }
            }
            bar_lgkm();   // T0' visible for next layer
        } else {
            float ssum = 0.f;
            #pragma unroll
            for (int m = 0; m < 2; m++) {
                #pragma unroll
                for (int r = 0; r < 16; r++) {
                    int np = (Mt0 + m) * 32 + (r & 3) + 8 * (r >> 2) + 4 * hh;
                    float h = fmaxf(acc[m][r] + bias, 0.f);
                    if (np < NPG) ssum += h;
                }
            }
            ssum += __shfl_xor(ssum, 32, 64);
            if (hh == 0) atomicAdd(&pool[fo], ssum);
            bar_lgkm();   // final barrier: pool visible to wave 0
        }
    }

    // ---------------- tail: wave 0 solo, wave-synchronous (no barriers) ----------------
    if (wg == 0) {
        float gv = pool[lane] * (1.0f / NPG);
        gv = (gv - bnm[lane]) * rsqrtf(bnv[lane] + 1e-5f) * bng[lane] + bnb[lane];
        gvn[lane] = gv;
        wait_lgkm();
        if (lane < 32) {
            float a = fc1b[lane];
            for (int f = 0; f < HF; f++) a += gvn[f] * fc1w[f * 32 + lane];
            zf[lane] = fmaxf(a, 0.f);
        }
        wait_lgkm();
        if (lane < 10) {
            float a = fc2b[lane];
            for (int k = 0; k < 32; k++) a += zf[k] * fc2w[k * 10 + lane];
            logits[lane] = a;
        }
        wait_lgkm();
        if (lane == 0) {
            float m = logits[0];
            for (int i = 1; i < 10; i++) m = fmaxf(m, logits[i]);
            float s = 0.f;
            for (int i = 0; i < 10; i++) s += expf(logits[i] - m);
            lsep[0] = m + logf(s);
        }
        wait_lgkm();
        if (lane < 10) out[g * 10 + lane] = logits[lane] - lsep[0];
    }
}

extern "C" void kernel_launch(void* const* d_in, const int* in_sizes, int n_in,
                              void* d_out, int out_size, void* d_ws, size_t ws_size,
                              hipStream_t stream) {
    const float* x    = (const float*)d_in[0];
    const int*   ei   = (const int*)d_in[1];
    const float* lmax = (const float*)d_in[3];
    const float* W1   = (const float*)d_in[4];
    const float* b1   = (const float*)d_in[5];
    const float* W2   = (const float*)d_in[6];
    const float* b2   = (const float*)d_in[7];
    const float* W3   = (const float*)d_in[8];
    const float* b3   = (const float*)d_in[9];
    const float* bng  = (const float*)d_in[10];
    const float* bnb  = (const float*)d_in[11];
    const float* bnm  = (const float*)d_in[12];
    const float* bnv  = (const float*)d_in[13];
    const float* fc1w = (const float*)d_in[14];
    const float* fc1b = (const float*)d_in[15];
    const float* fc2w = (const float*)d_in[16];
    const float* fc2b = (const float*)d_in[17];

    const int E = in_sizes[1] / 2;
    const int G = in_sizes[3];
    const int epg = E / G;

    unsigned short* Wt = (unsigned short*)d_ws;

    wconv<<<(WT_TOTAL + 255) / 256, 256, 0, stream>>>(W1, W2, W3, Wt);

    hipFuncSetAttribute((const void*)chebreg,
                        hipFuncAttributeMaxDynamicSharedMemorySize, SMEM_BYTES);

    chebreg<<<G, 256, SMEM_BYTES, stream>>>(x, ei, lmax, Wt, b1, b2, b3,
                                            bng, bnb, bnm, bnv, fc1w, fc1b, fc2w, fc2b,
                                            (float*)d_out, E, epg);
}